// Round 7
// baseline (61.958 us; speedup 1.0000x reference)
//
#include <hip/hip_runtime.h>
#include <hip/hip_bf16.h>
#include <cstdint>

// Problem dims (fixed by reference)
constexpr int B  = 8;
constexpr int LQ = 256;
constexpr int LK = 256;
constexpr int D  = 512;   // Dq == Dk
constexpr int A  = 256;

constexpr float NEG_INF   = -1e15f;               // matches reference -INFINITY
constexpr float LOG2E     = 1.4426950408889634f;
constexpr float TWO_LOG2E = 2.8853900817779268f;  // folded into W at staging

// GEMM tiling
constexpr int BR = 32;   // rows per block (q/k rows)
constexpr int BC = 64;   // cols per block (a)
constexpr int BK = 64;   // k-chunk
constexpr int XS_STRIDE = 34;
constexpr int WS_STRIDE = 68;

constexpr int QP_ELEMS = B * LQ * A;              // 524288

// ---------------------------------------------------------------------------
// Combined projection GEMM — EXACT round-2/6 structure (post-timing proven
// twice): loads issued at loop top, then barrier, stage, barrier, compute.
//   rows 0..2047   : qp'[row][a]  = (Q[row] . W1[a]) * TWO_LOG2E
//   rows 2048..4095: kp'[b][a][k] = (K[row] . W2[a]) * TWO_LOG2E  (transposed)
// ---------------------------------------------------------------------------
__global__ __launch_bounds__(256) void proj_gemm(const float* __restrict__ Q,
                                                 const float* __restrict__ Kin,
                                                 const float* __restrict__ W1,
                                                 const float* __restrict__ W2,
                                                 float* __restrict__ qp,
                                                 float* __restrict__ kp) {
    __shared__ float Xs[BK][XS_STRIDE];  // [k][r]  (transposed X tile)
    __shared__ float Ws[BK][WS_STRIDE];  // [k][c]  (transposed W tile, pre-scaled)

    const int t       = threadIdx.x;
    const int tile_c  = blockIdx.x & 3;        // 4 col tiles (A=256 / BC=64)
    const int tile_r  = blockIdx.x >> 2;       // 128 row tiles
    const int rowbase = tile_r * BR;           // 0..4064
    const bool isQ    = rowbase < 2048;

    const float* X = isQ ? (Q   + (size_t)rowbase * D)
                         : (Kin + (size_t)(rowbase - 2048) * D);
    const float* W = (isQ ? W1 : W2) + (size_t)(tile_c * BC) * D;

    // staging maps (coalesced global reads)
    const int sx_r = t >> 3;            // 0..31 (row within X tile)
    const int sx_k = (t & 7) * 8;       // 0..56 (k offset, 8 floats per thread)
    const int sw_c = t >> 2;            // 0..63 (a within W tile)
    const int sw_k = (t & 3) * 16;      // 0,16,32,48 (16 floats per thread)

    // compute maps: thread owns 2 rows x 4 cols
    const int cg = t & 15, rg = t >> 4;
    const int c0 = cg * 4, r0 = rg * 2;

    float acc[2][4] = {};

    for (int k0 = 0; k0 < D; k0 += BK) {
        // issue global loads early
        const float* xptr = X + (size_t)sx_r * D + k0 + sx_k;
        float4 xa = *(const float4*)(xptr);
        float4 xb = *(const float4*)(xptr + 4);
        const float* wptr = W + (size_t)sw_c * D + k0 + sw_k;
        float4 wv0 = *(const float4*)(wptr);
        float4 wv1 = *(const float4*)(wptr + 4);
        float4 wv2 = *(const float4*)(wptr + 8);
        float4 wv3 = *(const float4*)(wptr + 12);

        __syncthreads();  // previous chunk's compute done before overwrite

        Xs[sx_k + 0][sx_r] = xa.x;
        Xs[sx_k + 1][sx_r] = xa.y;
        Xs[sx_k + 2][sx_r] = xa.z;
        Xs[sx_k + 3][sx_r] = xa.w;
        Xs[sx_k + 4][sx_r] = xb.x;
        Xs[sx_k + 5][sx_r] = xb.y;
        Xs[sx_k + 6][sx_r] = xb.z;
        Xs[sx_k + 7][sx_r] = xb.w;

        Ws[sw_k +  0][sw_c] = wv0.x * TWO_LOG2E;
        Ws[sw_k +  1][sw_c] = wv0.y * TWO_LOG2E;
        Ws[sw_k +  2][sw_c] = wv0.z * TWO_LOG2E;
        Ws[sw_k +  3][sw_c] = wv0.w * TWO_LOG2E;
        Ws[sw_k +  4][sw_c] = wv1.x * TWO_LOG2E;
        Ws[sw_k +  5][sw_c] = wv1.y * TWO_LOG2E;
        Ws[sw_k +  6][sw_c] = wv1.z * TWO_LOG2E;
        Ws[sw_k +  7][sw_c] = wv1.w * TWO_LOG2E;
        Ws[sw_k +  8][sw_c] = wv2.x * TWO_LOG2E;
        Ws[sw_k +  9][sw_c] = wv2.y * TWO_LOG2E;
        Ws[sw_k + 10][sw_c] = wv2.z * TWO_LOG2E;
        Ws[sw_k + 11][sw_c] = wv2.w * TWO_LOG2E;
        Ws[sw_k + 12][sw_c] = wv3.x * TWO_LOG2E;
        Ws[sw_k + 13][sw_c] = wv3.y * TWO_LOG2E;
        Ws[sw_k + 14][sw_c] = wv3.z * TWO_LOG2E;
        Ws[sw_k + 15][sw_c] = wv3.w * TWO_LOG2E;

        __syncthreads();

#pragma unroll 8
        for (int kk = 0; kk < BK; ++kk) {
            float2 xr = *(const float2*)&Xs[kk][r0];
            float4 wr = *(const float4*)&Ws[kk][c0];
            acc[0][0] = fmaf(xr.x, wr.x, acc[0][0]);
            acc[0][1] = fmaf(xr.x, wr.y, acc[0][1]);
            acc[0][2] = fmaf(xr.x, wr.z, acc[0][2]);
            acc[0][3] = fmaf(xr.x, wr.w, acc[0][3]);
            acc[1][0] = fmaf(xr.y, wr.x, acc[1][0]);
            acc[1][1] = fmaf(xr.y, wr.y, acc[1][1]);
            acc[1][2] = fmaf(xr.y, wr.z, acc[1][2]);
            acc[1][3] = fmaf(xr.y, wr.w, acc[1][3]);
        }
    }

    const int cbase = tile_c * BC;
    if (isQ) {
#pragma unroll
        for (int i = 0; i < 2; ++i) {
            float4 v = make_float4(acc[i][0], acc[i][1], acc[i][2], acc[i][3]);
            *(float4*)(qp + (size_t)(rowbase + r0 + i) * A + cbase + c0) = v;
        }
    } else {
        // transpose 32x64 tile through LDS, write kp[b][a][k] coalesced along k
        __syncthreads();
        float* T = &Xs[0][0];  // 64*34 floats, exactly Xs capacity
#pragma unroll
        for (int i = 0; i < 2; ++i)
#pragma unroll
            for (int j = 0; j < 4; ++j)
                T[(c0 + j) * XS_STRIDE + (r0 + i)] = acc[i][j];
        __syncthreads();

        const int bb    = (rowbase - 2048) >> 8;
        const int kbase = rowbase & 255;
        const int kk    = t & 31;
        const int ag    = t >> 5;
        float* dst = kp + (size_t)bb * A * LK + (size_t)cbase * LK + kbase;
#pragma unroll
        for (int j = 0; j < 8; ++j) {
            int a2 = ag + 8 * j;
            dst[(size_t)a2 * LK + kk] = T[a2 * XS_STRIDE + kk];
        }
    }
}

// ---------------------------------------------------------------------------
// Fused score + mask + softmax. ONE q-row per block (grid 2048 -> up to
// 32 waves/CU). Shared-rcp pairs consecutive a's (same op count as TL=2).
// score'[q][k] = -2 * sum_a w3[a] / (1 + 2^(qp'[q][a]+kp'[a][k]))
// (row-constant sum(w3) dropped: softmax-invariant)
// ---------------------------------------------------------------------------
__global__ __launch_bounds__(256) void score_softmax(const float* __restrict__ qp,
                                                     const float* __restrict__ kpT,
                                                     const int* __restrict__ mask,
                                                     const float* __restrict__ w3,
                                                     float* __restrict__ out) {
    const int t   = threadIdx.x;            // k
    const int row = blockIdx.x;             // global q-row
    const int b   = row >> 8;

    const float* kpb = kpT + (size_t)b * A * LK;
    const float* q   = qp + (size_t)row * A;

    float acc = 0.f;

#pragma unroll 8
    for (int a = 0; a < A; a += 2) {
        float kv0 = kpb[a * LK + t];         // coalesced, L2-resident
        float kv1 = kpb[(a + 1) * LK + t];
        float u0  = q[a] + kv0;              // q[..], w3[..] uniform -> s_load
        float u1  = q[a + 1] + kv1;
        float e0  = __builtin_amdgcn_exp2f(u0);
        float e1  = __builtin_amdgcn_exp2f(u1);
        float a0  = 1.0f + e0;
        float a1  = 1.0f + e1;
        float rp  = __builtin_amdgcn_rcpf(a0 * a1);  // one rcp per 2 elements
        acc = fmaf(a1 * rp, w3[a], acc);
        acc = fmaf(a0 * rp, w3[a + 1], acc);
    }

    // mask + the -2 scale (applied once, preserves softmax ordering)
    float sc = (mask[(size_t)row * LK + t] == 0) ? NEG_INF : -2.0f * acc;

    // block softmax over 256 threads (4 waves); max slots [0..3], sum [4..7]
    __shared__ float red[8];
    const int wave = t >> 6, lane = t & 63;

    float m = sc;
#pragma unroll
    for (int off = 32; off > 0; off >>= 1)
        m = fmaxf(m, __shfl_xor(m, off));
    if (lane == 0) red[wave] = m;
    __syncthreads();
    float rmax = fmaxf(fmaxf(red[0], red[1]), fmaxf(red[2], red[3]));

    float p = __builtin_amdgcn_exp2f((sc - rmax) * LOG2E);

    float s = p;
#pragma unroll
    for (int off = 32; off > 0; off >>= 1)
        s += __shfl_xor(s, off);
    if (lane == 0) red[4 + wave] = s;
    __syncthreads();
    float sum = (red[4] + red[5]) + (red[6] + red[7]);

    out[(size_t)row * LK + t] = p * __builtin_amdgcn_rcpf(sum);
}

extern "C" void kernel_launch(void* const* d_in, const int* in_sizes, int n_in,
                              void* d_out, int out_size, void* d_ws, size_t ws_size,
                              hipStream_t stream) {
    const float* Q    = (const float*)d_in[0];   // [B,LQ,1,D]
    const float* K    = (const float*)d_in[1];   // [B,1,LK,D]
    const int*   mask = (const int*)d_in[2];     // [B,LQ,LK]
    const float* W1   = (const float*)d_in[3];   // [A,D]
    const float* W2   = (const float*)d_in[4];   // [A,D]
    const float* w3   = (const float*)d_in[5];   // [A]
    float* out = (float*)d_out;

    float* ws  = (float*)d_ws;
    float* qp  = ws;                     // [B*LQ][A]   (pre-scaled by 2*log2e)
    float* kpT = ws + QP_ELEMS;          // [B][A][LK]  (pre-scaled)

    proj_gemm<<<512, 256, 0, stream>>>(Q, K, W1, W2, qp, kpT);
    score_softmax<<<B * LQ, 256, 0, stream>>>(qp, kpT, mask, w3, out);
}

// Round 8
// 50.294 us; speedup vs baseline: 1.2319x; 1.2319x over previous
//
#include <hip/hip_runtime.h>
#include <hip/hip_bf16.h>
#include <cstdint>

// Problem dims (fixed by reference)
constexpr int B  = 8;
constexpr int LQ = 256;
constexpr int LK = 256;
constexpr int D  = 512;   // Dq == Dk
constexpr int A  = 256;

constexpr float NEG_INF   = -1e15f;               // matches reference -INFINITY
constexpr float LOG2E     = 1.4426950408889634f;
constexpr float TWO_LOG2E = 2.8853900817779268f;  // folded into W at staging

// GEMM tiling
constexpr int BR = 32;   // rows per block (q/k rows)
constexpr int BC = 64;   // cols per block (a)
constexpr int BK = 64;   // k-chunk
constexpr int XS_STRIDE = 34;
constexpr int WS_STRIDE = 68;

constexpr int QP_ELEMS = B * LQ * A;              // 524288

// ---------------------------------------------------------------------------
// Combined projection GEMM — EXACT round-2/6 sync structure (post-timing
// proven twice). ONLY change vs round 6: the epilogue applies exp2 to the
// accumulators (register-private), so the score kernel gets
//   eq[row][a] = 2^(qproj*2log2e),  ek[b][a][k] = 2^(kproj*2log2e)
// and can form 2^(u0) = eq*ek with one v_mul instead of add+exp2.
// ---------------------------------------------------------------------------
__global__ __launch_bounds__(256) void proj_gemm(const float* __restrict__ Q,
                                                 const float* __restrict__ Kin,
                                                 const float* __restrict__ W1,
                                                 const float* __restrict__ W2,
                                                 float* __restrict__ qp,
                                                 float* __restrict__ kp) {
    __shared__ float Xs[BK][XS_STRIDE];  // [k][r]  (transposed X tile)
    __shared__ float Ws[BK][WS_STRIDE];  // [k][c]  (transposed W tile, pre-scaled)

    const int t       = threadIdx.x;
    const int tile_c  = blockIdx.x & 3;        // 4 col tiles (A=256 / BC=64)
    const int tile_r  = blockIdx.x >> 2;       // 128 row tiles
    const int rowbase = tile_r * BR;           // 0..4064
    const bool isQ    = rowbase < 2048;

    const float* X = isQ ? (Q   + (size_t)rowbase * D)
                         : (Kin + (size_t)(rowbase - 2048) * D);
    const float* W = (isQ ? W1 : W2) + (size_t)(tile_c * BC) * D;

    // staging maps (coalesced global reads)
    const int sx_r = t >> 3;            // 0..31 (row within X tile)
    const int sx_k = (t & 7) * 8;       // 0..56 (k offset, 8 floats per thread)
    const int sw_c = t >> 2;            // 0..63 (a within W tile)
    const int sw_k = (t & 3) * 16;      // 0,16,32,48 (16 floats per thread)

    // compute maps: thread owns 2 rows x 4 cols
    const int cg = t & 15, rg = t >> 4;
    const int c0 = cg * 4, r0 = rg * 2;

    float acc[2][4] = {};

    for (int k0 = 0; k0 < D; k0 += BK) {
        // issue global loads early
        const float* xptr = X + (size_t)sx_r * D + k0 + sx_k;
        float4 xa = *(const float4*)(xptr);
        float4 xb = *(const float4*)(xptr + 4);
        const float* wptr = W + (size_t)sw_c * D + k0 + sw_k;
        float4 wv0 = *(const float4*)(wptr);
        float4 wv1 = *(const float4*)(wptr + 4);
        float4 wv2 = *(const float4*)(wptr + 8);
        float4 wv3 = *(const float4*)(wptr + 12);

        __syncthreads();  // previous chunk's compute done before overwrite

        Xs[sx_k + 0][sx_r] = xa.x;
        Xs[sx_k + 1][sx_r] = xa.y;
        Xs[sx_k + 2][sx_r] = xa.z;
        Xs[sx_k + 3][sx_r] = xa.w;
        Xs[sx_k + 4][sx_r] = xb.x;
        Xs[sx_k + 5][sx_r] = xb.y;
        Xs[sx_k + 6][sx_r] = xb.z;
        Xs[sx_k + 7][sx_r] = xb.w;

        Ws[sw_k +  0][sw_c] = wv0.x * TWO_LOG2E;
        Ws[sw_k +  1][sw_c] = wv0.y * TWO_LOG2E;
        Ws[sw_k +  2][sw_c] = wv0.z * TWO_LOG2E;
        Ws[sw_k +  3][sw_c] = wv0.w * TWO_LOG2E;
        Ws[sw_k +  4][sw_c] = wv1.x * TWO_LOG2E;
        Ws[sw_k +  5][sw_c] = wv1.y * TWO_LOG2E;
        Ws[sw_k +  6][sw_c] = wv1.z * TWO_LOG2E;
        Ws[sw_k +  7][sw_c] = wv1.w * TWO_LOG2E;
        Ws[sw_k +  8][sw_c] = wv2.x * TWO_LOG2E;
        Ws[sw_k +  9][sw_c] = wv2.y * TWO_LOG2E;
        Ws[sw_k + 10][sw_c] = wv2.z * TWO_LOG2E;
        Ws[sw_k + 11][sw_c] = wv2.w * TWO_LOG2E;
        Ws[sw_k + 12][sw_c] = wv3.x * TWO_LOG2E;
        Ws[sw_k + 13][sw_c] = wv3.y * TWO_LOG2E;
        Ws[sw_k + 14][sw_c] = wv3.z * TWO_LOG2E;
        Ws[sw_k + 15][sw_c] = wv3.w * TWO_LOG2E;

        __syncthreads();

#pragma unroll 8
        for (int kk = 0; kk < BK; ++kk) {
            float2 xr = *(const float2*)&Xs[kk][r0];
            float4 wr = *(const float4*)&Ws[kk][c0];
            acc[0][0] = fmaf(xr.x, wr.x, acc[0][0]);
            acc[0][1] = fmaf(xr.x, wr.y, acc[0][1]);
            acc[0][2] = fmaf(xr.x, wr.z, acc[0][2]);
            acc[0][3] = fmaf(xr.x, wr.w, acc[0][3]);
            acc[1][0] = fmaf(xr.y, wr.x, acc[1][0]);
            acc[1][1] = fmaf(xr.y, wr.y, acc[1][1]);
            acc[1][2] = fmaf(xr.y, wr.z, acc[1][2]);
            acc[1][3] = fmaf(xr.y, wr.w, acc[1][3]);
        }
    }

    // epilogue: exponentiate (register-private; sync structure untouched)
#pragma unroll
    for (int i = 0; i < 2; ++i)
#pragma unroll
        for (int j = 0; j < 4; ++j)
            acc[i][j] = __builtin_amdgcn_exp2f(acc[i][j]);

    const int cbase = tile_c * BC;
    if (isQ) {
#pragma unroll
        for (int i = 0; i < 2; ++i) {
            float4 v = make_float4(acc[i][0], acc[i][1], acc[i][2], acc[i][3]);
            *(float4*)(qp + (size_t)(rowbase + r0 + i) * A + cbase + c0) = v;
        }
    } else {
        // transpose 32x64 tile through LDS, write kp[b][a][k] coalesced along k
        __syncthreads();
        float* T = &Xs[0][0];  // 64*34 floats, exactly Xs capacity
#pragma unroll
        for (int i = 0; i < 2; ++i)
#pragma unroll
            for (int j = 0; j < 4; ++j)
                T[(c0 + j) * XS_STRIDE + (r0 + i)] = acc[i][j];
        __syncthreads();

        const int bb    = (rowbase - 2048) >> 8;
        const int kbase = rowbase & 255;
        const int kk    = t & 31;
        const int ag    = t >> 5;
        float* dst = kp + (size_t)bb * A * LK + (size_t)cbase * LK + kbase;
#pragma unroll
        for (int j = 0; j < 8; ++j) {
            int a2 = ag + 8 * j;
            dst[(size_t)a2 * LK + kk] = T[a2 * XS_STRIDE + kk];
        }
    }
}

// ---------------------------------------------------------------------------
// Fused score + mask + softmax — EXACT round-3/6 sync structure (post-timing
// proven twice). ONLY change: inputs are pre-exponentiated, so
//   2^(u) = eq * ek   (one v_mul replaces add+exp2).
// score'[q][k] = -2 * sum_a w3[a] / (1 + eq[q][a]*ek[a][k])
// (row-constant sum(w3) dropped: softmax-invariant)
// ---------------------------------------------------------------------------
__global__ __launch_bounds__(256) void score_softmax(const float* __restrict__ qp,
                                                     const float* __restrict__ kpT,
                                                     const int* __restrict__ mask,
                                                     const float* __restrict__ w3,
                                                     float* __restrict__ out) {
    const int t    = threadIdx.x;            // k
    const int row0 = blockIdx.x * 2;         // global q-row
    const int b    = row0 >> 8;

    const float* kpb = kpT + (size_t)b * A * LK;
    const float* q0  = qp + (size_t)row0 * A;

    float acc0 = 0.f, acc1 = 0.f;

#pragma unroll 8
    for (int a = 0; a < A; ++a) {
        float ek = kpb[a * LK + t];          // coalesced, L2-resident
        float w  = w3[a];                    // uniform -> s_load
        float e0 = q0[a] * ek;               // 2^(u0)  (q0[..] uniform)
        float e1 = q0[A + a] * ek;           // 2^(u1)
        float a0 = 1.0f + e0;
        float a1 = 1.0f + e1;
        float rp = __builtin_amdgcn_rcpf(a0 * a1);  // one rcp per 2 elements
        acc0 = fmaf(a1 * rp, w, acc0);
        acc1 = fmaf(a0 * rp, w, acc1);
    }

    // mask + the -2 scale (applied once, preserves softmax ordering)
    const int* mrow = mask + (size_t)row0 * LK;
    float sc0 = (mrow[t]      == 0) ? NEG_INF : -2.0f * acc0;
    float sc1 = (mrow[LK + t] == 0) ? NEG_INF : -2.0f * acc1;

    // block softmax over 256 threads (4 waves), 2 rows
    __shared__ float red[2][8];
    const int wave = t >> 6, lane = t & 63;

    float m0 = sc0, m1 = sc1;
#pragma unroll
    for (int off = 32; off > 0; off >>= 1) {
        m0 = fmaxf(m0, __shfl_xor(m0, off));
        m1 = fmaxf(m1, __shfl_xor(m1, off));
    }
    if (lane == 0) { red[0][wave] = m0; red[1][wave] = m1; }
    __syncthreads();
    float rmax0 = fmaxf(fmaxf(red[0][0], red[0][1]), fmaxf(red[0][2], red[0][3]));
    float rmax1 = fmaxf(fmaxf(red[1][0], red[1][1]), fmaxf(red[1][2], red[1][3]));
    __syncthreads();

    float p0 = __builtin_amdgcn_exp2f((sc0 - rmax0) * LOG2E);
    float p1 = __builtin_amdgcn_exp2f((sc1 - rmax1) * LOG2E);

    float s0 = p0, s1 = p1;
#pragma unroll
    for (int off = 32; off > 0; off >>= 1) {
        s0 += __shfl_xor(s0, off);
        s1 += __shfl_xor(s1, off);
    }
    if (lane == 0) { red[0][wave] = s0; red[1][wave] = s1; }
    __syncthreads();
    float sum0 = (red[0][0] + red[0][1]) + (red[0][2] + red[0][3]);
    float sum1 = (red[1][0] + red[1][1]) + (red[1][2] + red[1][3]);

    out[(size_t)row0 * LK + t]       = p0 * __builtin_amdgcn_rcpf(sum0);
    out[(size_t)(row0 + 1) * LK + t] = p1 * __builtin_amdgcn_rcpf(sum1);
}

extern "C" void kernel_launch(void* const* d_in, const int* in_sizes, int n_in,
                              void* d_out, int out_size, void* d_ws, size_t ws_size,
                              hipStream_t stream) {
    const float* Q    = (const float*)d_in[0];   // [B,LQ,1,D]
    const float* K    = (const float*)d_in[1];   // [B,1,LK,D]
    const int*   mask = (const int*)d_in[2];     // [B,LQ,LK]
    const float* W1   = (const float*)d_in[3];   // [A,D]
    const float* W2   = (const float*)d_in[4];   // [A,D]
    const float* w3   = (const float*)d_in[5];   // [A]
    float* out = (float*)d_out;

    float* ws  = (float*)d_ws;
    float* qp  = ws;                     // [B*LQ][A]   eq = 2^(qproj*2log2e)
    float* kpT = ws + QP_ELEMS;          // [B][A][LK]  ek = 2^(kproj*2log2e)

    proj_gemm<<<512, 256, 0, stream>>>(Q, K, W1, W2, qp, kpT);
    score_softmax<<<(B * LQ) / 2, 256, 0, stream>>>(qp, kpT, mask, w3, out);
}